// Round 3
// baseline (1478.118 us; speedup 1.0000x reference)
//
#include <hip/hip_runtime.h>
#include <math.h>

// ---------------- problem constants ----------------
#define N_DRUGS 4000
#define NN      8264            // total nodes
#define IN_DIM  1613
#define NRELS   4
#define DD1     1340
#define DD2     920
#define DD3     740
#define NEDGE   100000
#define NSEG    (NN * NRELS)    // 33056

// padded dims
#define MPAD    8320            // 65 * 128 (GEMM row tiles; rows >= NN are garbage-but-finite)
#define K1P     1632            // IN_DIM 1613 -> 51*32
#define K2P     1344            // DD1 1340 -> 42*32
#define K3P     928             // DD2 920  -> 29*32
#define N1PAD   1408            // DD1 -> 11*128
#define N2PAD   1024            // DD2 -> 8*128
#define N3PAD   768             // DD3 -> 6*128
#define MT      65              // MPAD/128

typedef unsigned short u16;
typedef __attribute__((ext_vector_type(8))) short short8;
typedef __attribute__((ext_vector_type(4))) float floatx4;

__device__ __forceinline__ u16 f2bf(float f) {
  union { float f; unsigned u; } v; v.f = f;
  unsigned u = v.u + 0x7fffu + ((v.u >> 16) & 1u);   // RNE
  return (u16)(u >> 16);
}
__device__ __forceinline__ float bf2f(u16 h) {
  union { unsigned u; float f; } v; v.u = ((unsigned)h) << 16;
  return v.f;
}

// async 16B global->LDS DMA (dest is wave-uniform base + lane*16, so the
// per-lane GLOBAL pointer carries any swizzle)
__device__ __forceinline__ void gl_lds16(const u16* g, u16* l) {
  __builtin_amdgcn_global_load_lds(
      (const __attribute__((address_space(1))) void*)g,
      (__attribute__((address_space(3))) void*)l, 16, 0, 0);
}

// ---------------- small utility kernels ----------------
__global__ void k_zero_i32(int* p, int n) {
  int i = blockIdx.x * 256 + threadIdx.x;
  if (i < n) p[i] = 0;
}

__global__ void k_zero_u16v(u16* p, long long nvec) {  // zeros 8 u16 per thread
  long long i = (long long)blockIdx.x * 256 + threadIdx.x;
  if (i < nvec) {
    short8 z = {0,0,0,0,0,0,0,0};
    *((short8*)p + i) = z;
  }
}

__global__ void k_copy_i32(const int* a, int* b, int n) {
  int i = blockIdx.x * 256 + threadIdx.x;
  if (i < n) b[i] = a[i];
}

// ---------------- CSR build (counting sort by segment = dst*4 + rel) ------
__global__ void k_hist(const int* __restrict__ ei, const int* __restrict__ et,
                       int* __restrict__ counts) {
  int e = blockIdx.x * 256 + threadIdx.x;
  if (e < NEDGE) {
    int dst = ei[NEDGE + e];
    atomicAdd(&counts[dst * 4 + et[e]], 1);
  }
}

__global__ void k_scan(const int* __restrict__ counts, int* __restrict__ offsets) {
  __shared__ int part[1024];
  int tid = threadIdx.x;
  const int chunk = (NSEG + 1023) / 1024;  // 33
  int lo = tid * chunk, hi = min(lo + chunk, NSEG);
  int s = 0;
  for (int i = lo; i < hi; i++) s += counts[i];
  part[tid] = s;
  __syncthreads();
  for (int off = 1; off < 1024; off <<= 1) {
    int v = (tid >= off) ? part[tid - off] : 0;
    __syncthreads();
    part[tid] += v;
    __syncthreads();
  }
  int base = (tid == 0) ? 0 : part[tid - 1];
  for (int i = lo; i < hi; i++) { offsets[i] = base; base += counts[i]; }
  if (tid == 0) offsets[NSEG] = part[1023];
}

__global__ void k_fill(const int* __restrict__ ei, const int* __restrict__ et,
                       int* __restrict__ cursors, int* __restrict__ ssrc) {
  int e = blockIdx.x * 256 + threadIdx.x;
  if (e < NEDGE) {
    int src = ei[e], dst = ei[NEDGE + e];
    int pos = atomicAdd(&cursors[dst * 4 + et[e]], 1);
    if (pos < NEDGE) ssrc[pos] = src;
  }
}

// ---------------- feature builder: xf = concat(x, gene_emb) in bf16 -------
__global__ void k_build_xf(const float* __restrict__ x, const float* __restrict__ gene,
                           u16* __restrict__ xf) {
  int n = blockIdx.x;
  const float* srow = (n < N_DRUGS) ? (x + (long long)n * IN_DIM)
                                    : (gene + (long long)(n - N_DRUGS) * IN_DIM);
  u16* dst = xf + (long long)n * K1P;
  for (int f = threadIdx.x; f < K1P; f += 256)
    dst[f] = (f < IN_DIM) ? f2bf(srow[f]) : (u16)0;
}

// f32 (K x N, row-major) -> bf16 out[n][kofs+k], tiled transpose
__global__ void k_transpose(const float* __restrict__ in, int K, int N,
                            u16* __restrict__ out, int ldd, int kofs) {
  __shared__ float t[32][33];
  int k0 = blockIdx.x * 32, n0 = blockIdx.y * 32;
  int tx = threadIdx.x, ty = threadIdx.y;
  for (int i = ty; i < 32; i += 8) {
    int k = k0 + i, n = n0 + tx;
    t[i][tx] = (k < K && n < N) ? in[(long long)k * N + n] : 0.f;
  }
  __syncthreads();
  for (int i = ty; i < 32; i += 8) {
    int n = n0 + i, k = k0 + tx;
    if (n < N && k < K) out[(long long)n * ldd + kofs + k] = f2bf(t[tx][i]);
  }
}

// per-(node, rel r) mean over gathered T rows, accumulate into bf16 HACC
__global__ void k_agg(const u16* __restrict__ T, int ldT,
                      u16* __restrict__ HACC, int ldH, int F,
                      const int* __restrict__ offsets, const int* __restrict__ ssrc,
                      int r, int init) {
  int node = blockIdx.x;
  int seg = node * 4 + r;
  int beg = offsets[seg], end = offsets[seg + 1];
  float inv = (end > beg) ? 1.0f / (float)(end - beg) : 0.0f;
  u16* o = HACC + (long long)node * ldH;
  for (int f = threadIdx.x; f < F; f += 256) {
    float acc = 0.f;
    for (int e = beg; e < end; e++)
      acc += bf2f(T[(long long)ssrc[e] * ldT + f]);
    acc *= inv;
    if (!init) acc += bf2f(o[f]);
    o[f] = f2bf(acc);
  }
}

// ---------------- bf16 MFMA GEMM: C = act(A @ B^T + Cacc + bias) ----------
// m97 structure: global_load_lds width=16 staging into unpadded [128][32]
// tiles (64B rows); fragment reads chunk-swizzled (swizzle carried by the
// per-lane global pointer since the DMA's LDS side is fixed lane-order).
// 1D grid, XCD-chunked: XCD r owns m-tiles with m % 8 == r, n fastest ->
// A-tile pinned in that XCD's L2 across the n sweep.
#define BK 32

__global__ __launch_bounds__(256)
void k_gemm(const u16* __restrict__ A, int lda,
            const u16* __restrict__ B, int ldb, int ksteps,
            void* __restrict__ Cout, int ldc,
            const u16* __restrict__ Cacc, int ldacc,
            int nreal, int nlimit, int mlimit,
            const float* __restrict__ bias, int relu, int f32out,
            int mtiles, int ntiles)
{
  int f = blockIdx.x;
  int xr = f & 7, q = f >> 3;
  int Ma = (mtiles + 7) >> 3;
  int ncol = q / Ma;
  int mi = ((q - ncol * Ma) << 3) + xr;
  if (mi >= mtiles) return;

  __shared__ __align__(16) u16 At[128 * BK];
  __shared__ __align__(16) u16 Bt[128 * BK];
  int tid = threadIdx.x;
  int wave = tid >> 6, lane = tid & 63;
  int wm = (wave >> 1) << 6, wn = (wave & 1) << 6;
  int qd = lane >> 4, l16 = lane & 15;

  const u16* Ag = A + (long long)mi * 128 * lda;
  const u16* Bg = B + (long long)ncol * 128 * ldb;

  // staging geometry: each wave call covers 16 rows (64 lanes x 16B)
  int rl0 = wave * 16 + (lane >> 2);       // rows 0..63 (call0) / +64 (call1)
  int cc = lane & 3;                        // 16B chunk within 64B row
  int sw = (cc ^ ((rl0 >> 1) & 3)) * 8;     // swizzled global chunk (same for +64)
  const u16* gA0 = Ag + (long long)rl0 * lda + sw;
  const u16* gA1 = Ag + (long long)(rl0 + 64) * lda + sw;
  const u16* gB0 = Bg + (long long)rl0 * ldb + sw;
  const u16* gB1 = Bg + (long long)(rl0 + 64) * ldb + sw;
  u16* lA0 = At + rl0 * BK + cc * 8;
  u16* lA1 = At + (rl0 + 64) * BK + cc * 8;
  u16* lB0 = Bt + rl0 * BK + cc * 8;
  u16* lB1 = Bt + (rl0 + 64) * BK + cc * 8;

  int rsw = ((l16 >> 1) & 3);               // fragment-read chunk swizzle

  floatx4 acc[4][4] = {};

  for (int ks = 0; ks < ksteps; ks++) {
    int kb = ks * BK;
    __syncthreads();
    gl_lds16(gA0 + kb, lA0);
    gl_lds16(gA1 + kb, lA1);
    gl_lds16(gB0 + kb, lB0);
    gl_lds16(gB1 + kb, lB1);
    __syncthreads();
    short8 af[4], bfr[4];
#pragma unroll
    for (int i = 0; i < 4; i++)
      af[i] = *(const short8*)(At + (wm + i * 16 + l16) * BK + ((qd ^ rsw) << 3));
#pragma unroll
    for (int j = 0; j < 4; j++)
      bfr[j] = *(const short8*)(Bt + (wn + j * 16 + l16) * BK + ((qd ^ rsw) << 3));
#pragma unroll
    for (int i = 0; i < 4; i++)
#pragma unroll
      for (int j = 0; j < 4; j++)
        acc[i][j] = __builtin_amdgcn_mfma_f32_16x16x32_bf16(af[i], bfr[j], acc[i][j], 0, 0, 0);
  }

  // epilogue
#pragma unroll
  for (int i = 0; i < 4; i++) {
#pragma unroll
    for (int j = 0; j < 4; j++) {
      int col = ncol * 128 + wn + j * 16 + l16;
      if (col >= nlimit) continue;
      float bv = (bias && col < nreal) ? bias[col] : 0.f;
#pragma unroll
      for (int rg = 0; rg < 4; rg++) {
        int row = mi * 128 + wm + i * 16 + qd * 4 + rg;
        if (row >= mlimit) continue;
        float v = 0.f;
        if (col < nreal) {
          v = acc[i][j][rg] + bv;
          if (Cacc) v += bf2f(Cacc[(long long)row * ldacc + col]);
          if (relu) v = fmaxf(v, 0.f);
        }
        if (f32out) ((float*)Cout)[(long long)row * ldc + col] = v;
        else        ((u16*)Cout)[(long long)row * ldc + col] = f2bf(v);
      }
    }
  }
}

// ---------------- final tiny layer: logits + log_softmax ----------------
__global__ void k_lin2(const float* __restrict__ emb, const float* __restrict__ w,
                       const float* __restrict__ b, float* __restrict__ out) {
  int node = blockIdx.x * 4 + (threadIdx.x >> 6);
  int lane = threadIdx.x & 63;
  if (node >= NN) return;
  const float* e = emb + (long long)node * DD3;
  float a0 = 0.f, a1 = 0.f;
  for (int f = lane; f < DD3; f += 64) {
    float v = e[f];
    a0 += v * w[2 * f];
    a1 += v * w[2 * f + 1];
  }
  for (int off = 32; off > 0; off >>= 1) {
    a0 += __shfl_down(a0, off);
    a1 += __shfl_down(a1, off);
  }
  if (lane == 0) {
    a0 += b[0]; a1 += b[1];
    float m = fmaxf(a0, a1);
    float ls = m + logf(expf(a0 - m) + expf(a1 - m));
    out[(long long)node * 2]     = a0 - ls;
    out[(long long)node * 2 + 1] = a1 - ls;
  }
}

// ---------------- launch ----------------
extern "C" void kernel_launch(void* const* d_in, const int* in_sizes, int n_in,
                              void* d_out, int out_size, void* d_ws, size_t ws_size,
                              hipStream_t stream)
{
  const float* x      = (const float*)d_in[0];
  const float* gene   = (const float*)d_in[1];
  const float* w_rel1 = (const float*)d_in[2];
  const float* root1  = (const float*)d_in[3];
  const float* b1     = (const float*)d_in[4];
  const float* w_rel2 = (const float*)d_in[5];
  const float* root2  = (const float*)d_in[6];
  const float* b2     = (const float*)d_in[7];
  const float* lin1_w = (const float*)d_in[8];
  const float* lin1_b = (const float*)d_in[9];
  const float* lin2_w = (const float*)d_in[10];
  const float* lin2_b = (const float*)d_in[11];
  const int*   ei     = (const int*)d_in[12];
  const int*   et     = (const int*)d_in[13];
  float* out = (float*)d_out;

  // workspace layout (~133 MB total)
  char* ws = (char*)d_ws;
  size_t off = 0;
  auto alloc = [&](size_t bytes) -> void* {
    void* p = ws + off;
    off += (bytes + 255) & ~(size_t)255;
    return p;
  };
  const size_t W1SLOT = (size_t)N1PAD * K1P;   // per-relation weight slot (elems)
  const size_t W2SLOT = (size_t)N2PAD * K2P;
  u16* XF   = (u16*)alloc((size_t)MPAD * K1P * 2);   // also reused as H2 (MPAD x K3P)
  u16* T    = (u16*)alloc((size_t)MPAD * K2P * 2);   // per-relation transform output
  u16* HACC = (u16*)alloc((size_t)MPAD * K2P * 2);   // bf16 aggregation accumulator
  u16* H1   = (u16*)alloc((size_t)MPAD * K2P * 2);
  u16* W1T  = (u16*)alloc(5 * W1SLOT * 2);           // r0..r3, root
  u16* W2T  = (u16*)alloc(5 * W2SLOT * 2);
  u16* W3T  = (u16*)alloc((size_t)N3PAD * K3P * 2);
  int* counts  = (int*)alloc((NSEG + 1) * 4);
  int* offsets = (int*)alloc((NSEG + 1) * 4);
  int* cursors = (int*)alloc((size_t)NSEG * 4);
  int* ssrc    = (int*)alloc((size_t)NEDGE * 4);
  u16* H2 = XF;                                      // alias: XF dead after layer-1 root GEMM
  float* emb = out + 2 * NN;   // d_out = [log_softmax 8264x2][emb 8264x740]

  if (off > ws_size) return;   // diagnostic: stub-like absmax instead of GPU fault

  // ---- CSR build ----
  k_zero_i32<<<(NSEG + 1 + 255) / 256, 256, 0, stream>>>(counts, NSEG + 1);
  k_hist<<<(NEDGE + 255) / 256, 256, 0, stream>>>(ei, et, counts);
  k_scan<<<1, 1024, 0, stream>>>(counts, offsets);
  k_copy_i32<<<(NSEG + 255) / 256, 256, 0, stream>>>(offsets, cursors, NSEG);
  k_fill<<<(NEDGE + 255) / 256, 256, 0, stream>>>(ei, et, cursors, ssrc);

  // ---- weights: zero pads then transpose into bf16 N x K slots ----
  long long wvec = (5LL * W1SLOT + 5LL * W2SLOT + (long long)N3PAD * K3P) / 8;
  k_zero_u16v<<<(unsigned)((wvec + 255) / 256), 256, 0, stream>>>(W1T, wvec);
  dim3 tb(32, 8);
  for (int r = 0; r < 4; r++)
    k_transpose<<<dim3((IN_DIM + 31) / 32, (DD1 + 31) / 32), tb, 0, stream>>>(
        w_rel1 + (long long)r * IN_DIM * DD1, IN_DIM, DD1, W1T + r * W1SLOT, K1P, 0);
  k_transpose<<<dim3((IN_DIM + 31) / 32, (DD1 + 31) / 32), tb, 0, stream>>>(
      root1, IN_DIM, DD1, W1T + 4 * W1SLOT, K1P, 0);
  for (int r = 0; r < 4; r++)
    k_transpose<<<dim3((DD1 + 31) / 32, (DD2 + 31) / 32), tb, 0, stream>>>(
        w_rel2 + (long long)r * DD1 * DD2, DD1, DD2, W2T + r * W2SLOT, K2P, 0);
  k_transpose<<<dim3((DD1 + 31) / 32, (DD2 + 31) / 32), tb, 0, stream>>>(
      root2, DD1, DD2, W2T + 4 * W2SLOT, K2P, 0);
  k_transpose<<<dim3((DD2 + 31) / 32, (DD3 + 31) / 32), tb, 0, stream>>>(
      lin1_w, DD2, DD3, W3T, K3P, 0);

  // ---- input features ----
  k_build_xf<<<NN, 256, 0, stream>>>(x, gene, XF);

  // XCD-chunked 1D grids: 8 * ceil(MT/8) * ntiles
  const int Ma = (MT + 7) / 8;                 // 9
  const int g1 = 8 * Ma * (N1PAD / 128);       // 792
  const int g2 = 8 * Ma * (N2PAD / 128);       // 576
  const int g3 = 8 * Ma * (N3PAD / 128);       // 432

  // ---- layer 1: per-relation transform + mean-aggregate, then root ----
  for (int r = 0; r < 4; r++) {
    k_gemm<<<g1, 256, 0, stream>>>(
        XF, K1P, W1T + r * W1SLOT, K1P, K1P / 32,
        T, K2P, (const u16*)nullptr, 0, K2P, K2P, MPAD,
        (const float*)nullptr, 0, 0, MT, N1PAD / 128);
    k_agg<<<NN, 256, 0, stream>>>(T, K2P, HACC, K2P, DD1, offsets, ssrc, r, r == 0);
  }
  k_gemm<<<g1, 256, 0, stream>>>(
      XF, K1P, W1T + 4 * W1SLOT, K1P, K1P / 32,
      H1, K2P, HACC, K2P, DD1, K2P, MPAD, b1, 1, 0, MT, N1PAD / 128);

  // ---- layer 2 ----
  for (int r = 0; r < 4; r++) {
    k_gemm<<<g2, 256, 0, stream>>>(
        H1, K2P, W2T + r * W2SLOT, K2P, K2P / 32,
        T, K3P, (const u16*)nullptr, 0, K3P, K3P, MPAD,
        (const float*)nullptr, 0, 0, MT, N2PAD / 128);
    k_agg<<<NN, 256, 0, stream>>>(T, K3P, HACC, K3P, DD2, offsets, ssrc, r, r == 0);
  }
  k_gemm<<<g2, 256, 0, stream>>>(
      H1, K2P, W2T + 4 * W2SLOT, K2P, K2P / 32,
      H2, K3P, HACC, K3P, DD2, K3P, MPAD, b2, 1, 0, MT, N2PAD / 128);

  // ---- lin1 -> emb (f32, straight into d_out) ----
  k_gemm<<<g3, 256, 0, stream>>>(
      H2, K3P, W3T, K3P, K3P / 32,
      emb, DD3, (const u16*)nullptr, 0, DD3, DD3, NN, lin1_b, 1, 1, MT, N3PAD / 128);

  // ---- lin2 + log_softmax ----
  k_lin2<<<(NN + 3) / 4, 256, 0, stream>>>(emb, lin2_w, lin2_b, out);
}

// Round 4
// 1222.926 us; speedup vs baseline: 1.2087x; 1.2087x over previous
//
#include <hip/hip_runtime.h>
#include <math.h>

// ---------------- problem constants ----------------
#define N_DRUGS 4000
#define NN      8264            // total nodes
#define IN_DIM  1613
#define NRELS   4
#define DD1     1340
#define DD2     920
#define DD3     740
#define NEDGE   100000
#define NSEG    (NN * NRELS)    // 33056

// padded dims
#define MPAD    8320            // 65 * 128 m-tiles (rows >= NN read as garbage, outputs masked)
#define K1P     1632            // IN_DIM -> 51*32
#define K2P     1344            // DD1 -> 42*32
#define K3P     928             // DD2 -> 29*32
#define N1PAD   1408            // DD1 -> 11*128 (weight slot width)
#define N2PAD   1024            // DD2 -> 8*128
#define N3PAD   768             // DD3 -> 6*128
#define MT      65              // MPAD/128

typedef unsigned short u16;
typedef __attribute__((ext_vector_type(8))) short short8;
typedef __attribute__((ext_vector_type(4))) float floatx4;

__device__ __forceinline__ u16 f2bf(float f) {
  union { float f; unsigned u; } v; v.f = f;
  unsigned u = v.u + 0x7fffu + ((v.u >> 16) & 1u);   // RNE
  return (u16)(u >> 16);
}
__device__ __forceinline__ float bf2f(u16 h) {
  union { unsigned u; float f; } v; v.u = ((unsigned)h) << 16;
  return v.f;
}

// ---------------- small utility kernels ----------------
__global__ void k_zero_i32(int* p, int n) {
  int i = blockIdx.x * 256 + threadIdx.x;
  if (i < n) p[i] = 0;
}

__global__ void k_zero_u16v(u16* p, long long nvec) {  // zeros 8 u16 per thread
  long long i = (long long)blockIdx.x * 256 + threadIdx.x;
  if (i < nvec) {
    short8 z = {0,0,0,0,0,0,0,0};
    *((short8*)p + i) = z;
  }
}

__global__ void k_copy_i32(const int* a, int* b, int n) {
  int i = blockIdx.x * 256 + threadIdx.x;
  if (i < n) b[i] = a[i];
}

// ---------------- CSR build (counting sort by segment = dst*4 + rel) ------
__global__ void k_hist(const int* __restrict__ ei, const int* __restrict__ et,
                       int* __restrict__ counts) {
  int e = blockIdx.x * 256 + threadIdx.x;
  if (e < NEDGE) {
    int dst = ei[NEDGE + e];
    atomicAdd(&counts[dst * 4 + et[e]], 1);
  }
}

__global__ void k_scan(const int* __restrict__ counts, int* __restrict__ offsets) {
  __shared__ int part[1024];
  int tid = threadIdx.x;
  const int chunk = (NSEG + 1023) / 1024;  // 33
  int lo = tid * chunk, hi = min(lo + chunk, NSEG);
  int s = 0;
  for (int i = lo; i < hi; i++) s += counts[i];
  part[tid] = s;
  __syncthreads();
  for (int off = 1; off < 1024; off <<= 1) {
    int v = (tid >= off) ? part[tid - off] : 0;
    __syncthreads();
    part[tid] += v;
    __syncthreads();
  }
  int base = (tid == 0) ? 0 : part[tid - 1];
  for (int i = lo; i < hi; i++) { offsets[i] = base; base += counts[i]; }
  if (tid == 0) offsets[NSEG] = part[1023];
}

__global__ void k_fill(const int* __restrict__ ei, const int* __restrict__ et,
                       int* __restrict__ cursors, int* __restrict__ ssrc) {
  int e = blockIdx.x * 256 + threadIdx.x;
  if (e < NEDGE) {
    int src = ei[e], dst = ei[NEDGE + e];
    int pos = atomicAdd(&cursors[dst * 4 + et[e]], 1);
    if (pos < NEDGE) ssrc[pos] = src;
  }
}

// ---------------- feature builder: xf = concat(x, gene_emb) in bf16 -------
__global__ void k_build_xf(const float* __restrict__ x, const float* __restrict__ gene,
                           u16* __restrict__ xf) {
  int n = blockIdx.x;
  const float* srow = (n < N_DRUGS) ? (x + (long long)n * IN_DIM)
                                    : (gene + (long long)(n - N_DRUGS) * IN_DIM);
  u16* dst = xf + (long long)n * K1P;
  for (int f = threadIdx.x; f < K1P; f += 256)
    dst[f] = (f < IN_DIM) ? f2bf(srow[f]) : (u16)0;
}

// f32 (K x N, row-major) -> bf16 out[n][k], tiled transpose
__global__ void k_transpose(const float* __restrict__ in, int K, int N,
                            u16* __restrict__ out, int ldd) {
  __shared__ float t[32][33];
  int k0 = blockIdx.x * 32, n0 = blockIdx.y * 32;
  int tx = threadIdx.x, ty = threadIdx.y;
  for (int i = ty; i < 32; i += 8) {
    int k = k0 + i, n = n0 + tx;
    t[i][tx] = (k < K && n < N) ? in[(long long)k * N + n] : 0.f;
  }
  __syncthreads();
  for (int i = ty; i < 32; i += 8) {
    int n = n0 + i, k = k0 + tx;
    if (n < N && k < K) out[(long long)n * ldd + k] = f2bf(t[tx][i]);
  }
}

// per-node mean over gathered T rows for TWO relations (slots 0 and slotOfs),
// accumulate into bf16 HACC
__global__ void k_agg2(const u16* __restrict__ T, int ldT, int slotOfs,
                       u16* __restrict__ HACC, int ldH, int F,
                       const int* __restrict__ offsets, const int* __restrict__ ssrc,
                       int rbase, int init) {
  int node = blockIdx.x;
  int s0 = node * 4 + rbase;
  int b0 = offsets[s0],     e0 = offsets[s0 + 1];
  int b1 = offsets[s0 + 1], e1 = offsets[s0 + 2];
  float inv0 = (e0 > b0) ? 1.0f / (float)(e0 - b0) : 0.0f;
  float inv1 = (e1 > b1) ? 1.0f / (float)(e1 - b1) : 0.0f;
  u16* o = HACC + (long long)node * ldH;
  for (int f = threadIdx.x; f < F; f += 256) {
    float a0 = 0.f, a1 = 0.f;
    for (int e = b0; e < e0; e++)
      a0 += bf2f(T[(long long)ssrc[e] * ldT + f]);
    for (int e = b1; e < e1; e++)
      a1 += bf2f(T[(long long)ssrc[e] * ldT + slotOfs + f]);
    float v = a0 * inv0 + a1 * inv1;
    if (!init) v += bf2f(o[f]);
    o[f] = f2bf(v);
  }
}

// ---------------- bf16 MFMA GEMM: C = act(A @ B^T + Cacc + bias) ----------
// VGPR staging with explicit next-tile register prefetch (hides global latency
// behind the MFMA block without needing the DMA path, which can't cross the
// barrier). Unpadded [128][32] LDS tiles; chunk-swizzle (cc ^ ((row>>1)&3))
// on the write side, matching qd^rsw on the read side -> 0 bank conflicts
// (verified round 3). XCD-chunked 1D grid: XCD r owns m-tiles m%8==r, n slow.
__global__ __launch_bounds__(256)
void k_gemm(const u16* __restrict__ A, int lda,
            const u16* __restrict__ B, int ldb, int ksteps,
            void* __restrict__ Cout, int ldc,
            const u16* __restrict__ Cacc, int ldacc,
            int nreal, int nlimit, int mlimit,
            const float* __restrict__ bias, int relu, int f32out,
            int mtiles, int ntiles)
{
  int f = blockIdx.x;
  int xr = f & 7, q = f >> 3;
  int Ma = (mtiles + 7) >> 3;
  int ncol = q / Ma;
  int mi = ((q - ncol * Ma) << 3) + xr;
  if (mi >= mtiles) return;

  __shared__ __align__(16) u16 At[128 * 32];
  __shared__ __align__(16) u16 Bt[128 * 32];
  int tid = threadIdx.x;
  int wave = tid >> 6, lane = tid & 63;
  int wm = (wave >> 1) << 6, wn = (wave & 1) << 6;
  int qd = lane >> 4, l16 = lane & 15;

  const u16* Ag = A + (long long)mi * 128 * lda;
  const u16* Bg = B + (long long)ncol * 128 * ldb;

  int row = tid >> 2, cc = tid & 3;           // 64 rows x 4 chunks per 256 threads
  int swc = cc ^ ((row >> 1) & 3);            // same swizzle for row and row+64
  const u16* gA0 = Ag + (long long)row * lda + cc * 8;
  const u16* gA1 = Ag + (long long)(row + 64) * lda + cc * 8;
  const u16* gB0 = Bg + (long long)row * ldb + cc * 8;
  const u16* gB1 = Bg + (long long)(row + 64) * ldb + cc * 8;
  u16* sA0 = At + row * 32 + swc * 8;
  u16* sA1 = At + (row + 64) * 32 + swc * 8;
  u16* sB0 = Bt + row * 32 + swc * 8;
  u16* sB1 = Bt + (row + 64) * 32 + swc * 8;
  int rsw = (l16 >> 1) & 3;

  short8 pa0 = *(const short8*)gA0;
  short8 pa1 = *(const short8*)gA1;
  short8 pb0 = *(const short8*)gB0;
  short8 pb1 = *(const short8*)gB1;

  floatx4 acc[4][4] = {};

  for (int ks = 0; ks < ksteps; ks++) {
    __syncthreads();
    *(short8*)sA0 = pa0; *(short8*)sA1 = pa1;
    *(short8*)sB0 = pb0; *(short8*)sB1 = pb1;
    __syncthreads();
    if (ks + 1 < ksteps) {                    // prefetch next k-tile into regs
      int kb = (ks + 1) * 32;
      pa0 = *(const short8*)(gA0 + kb); pa1 = *(const short8*)(gA1 + kb);
      pb0 = *(const short8*)(gB0 + kb); pb1 = *(const short8*)(gB1 + kb);
    }
    short8 af[4], bfr[4];
#pragma unroll
    for (int i = 0; i < 4; i++)
      af[i] = *(const short8*)(At + (wm + i * 16 + l16) * 32 + ((qd ^ rsw) << 3));
#pragma unroll
    for (int j = 0; j < 4; j++)
      bfr[j] = *(const short8*)(Bt + (wn + j * 16 + l16) * 32 + ((qd ^ rsw) << 3));
#pragma unroll
    for (int i = 0; i < 4; i++)
#pragma unroll
      for (int j = 0; j < 4; j++)
        acc[i][j] = __builtin_amdgcn_mfma_f32_16x16x32_bf16(af[i], bfr[j], acc[i][j], 0, 0, 0);
  }

  // epilogue
#pragma unroll
  for (int i = 0; i < 4; i++) {
#pragma unroll
    for (int j = 0; j < 4; j++) {
      int col = ncol * 128 + wn + j * 16 + l16;
      if (col >= nlimit) continue;
      float bv = (bias && col < nreal) ? bias[col] : 0.f;
#pragma unroll
      for (int rg = 0; rg < 4; rg++) {
        int rowc = mi * 128 + wm + i * 16 + qd * 4 + rg;
        if (rowc >= mlimit) continue;
        float v = 0.f;
        if (col < nreal) {
          v = acc[i][j][rg] + bv;
          if (Cacc) v += bf2f(Cacc[(long long)rowc * ldacc + col]);
          if (relu) v = fmaxf(v, 0.f);
        }
        if (f32out) ((float*)Cout)[(long long)rowc * ldc + col] = v;
        else        ((u16*)Cout)[(long long)rowc * ldc + col] = f2bf(v);
      }
    }
  }
}

// ---------------- final tiny layer: logits + log_softmax ----------------
__global__ void k_lin2(const float* __restrict__ emb, const float* __restrict__ w,
                       const float* __restrict__ b, float* __restrict__ out) {
  int node = blockIdx.x * 4 + (threadIdx.x >> 6);
  int lane = threadIdx.x & 63;
  if (node >= NN) return;
  const float* e = emb + (long long)node * DD3;
  float a0 = 0.f, a1 = 0.f;
  for (int f = lane; f < DD3; f += 64) {
    float v = e[f];
    a0 += v * w[2 * f];
    a1 += v * w[2 * f + 1];
  }
  for (int off = 32; off > 0; off >>= 1) {
    a0 += __shfl_down(a0, off);
    a1 += __shfl_down(a1, off);
  }
  if (lane == 0) {
    a0 += b[0]; a1 += b[1];
    float m = fmaxf(a0, a1);
    float ls = m + logf(expf(a0 - m) + expf(a1 - m));
    out[(long long)node * 2]     = a0 - ls;
    out[(long long)node * 2 + 1] = a1 - ls;
  }
}

// ---------------- launch ----------------
extern "C" void kernel_launch(void* const* d_in, const int* in_sizes, int n_in,
                              void* d_out, int out_size, void* d_ws, size_t ws_size,
                              hipStream_t stream)
{
  const float* x      = (const float*)d_in[0];
  const float* gene   = (const float*)d_in[1];
  const float* w_rel1 = (const float*)d_in[2];
  const float* root1  = (const float*)d_in[3];
  const float* b1     = (const float*)d_in[4];
  const float* w_rel2 = (const float*)d_in[5];
  const float* root2  = (const float*)d_in[6];
  const float* b2     = (const float*)d_in[7];
  const float* lin1_w = (const float*)d_in[8];
  const float* lin1_b = (const float*)d_in[9];
  const float* lin2_w = (const float*)d_in[10];
  const float* lin2_b = (const float*)d_in[11];
  const int*   ei     = (const int*)d_in[12];
  const int*   et     = (const int*)d_in[13];
  float* out = (float*)d_out;

  // workspace layout (~142 MB total; known-good budget 155.6 MB)
  char* ws = (char*)d_ws;
  size_t off = 0;
  auto alloc = [&](size_t bytes) -> void* {
    void* p = ws + off;
    off += (bytes + 255) & ~(size_t)255;
    return p;
  };
  const size_t W1SLOT = (size_t)N1PAD * K1P;
  const size_t W2SLOT = (size_t)N2PAD * K2P;
  u16* XF   = (u16*)alloc((size_t)NN * K1P * 2);     // reused as H2 (NN x K3P) later
  u16* T    = (u16*)alloc((size_t)NN * 2 * N1PAD * 2); // 2-slot transform output
  u16* HACC = (u16*)alloc((size_t)NN * K2P * 2);     // bf16 aggregation accumulator
  u16* H1   = (u16*)alloc((size_t)NN * K2P * 2);
  u16* W1P  = (u16*)alloc(2 * W1SLOT * 2);           // pair slot (reused r0r1 -> r2r3)
  u16* W1R  = (u16*)alloc(W1SLOT * 2);               // root slot
  u16* W2P  = (u16*)alloc(2 * W2SLOT * 2);
  u16* W2R  = (u16*)alloc(W2SLOT * 2);
  u16* W3T  = (u16*)alloc((size_t)N3PAD * K3P * 2);
  int* counts  = (int*)alloc((NSEG + 1) * 4);        // reused as cursors
  int* offsets = (int*)alloc((NSEG + 1) * 4);
  int* ssrc    = (int*)alloc((size_t)NEDGE * 4);
  u16* H2 = XF;                                      // alias: XF dead after L1 root GEMM
  float* emb = out + 2 * NN;   // d_out = [log_softmax 8264x2][emb 8264x740]

  if (off > ws_size) return;   // diagnostic: stub-like absmax instead of GPU fault

  // ---- CSR build ----
  k_zero_i32<<<(NSEG + 1 + 255) / 256, 256, 0, stream>>>(counts, NSEG + 1);
  k_hist<<<(NEDGE + 255) / 256, 256, 0, stream>>>(ei, et, counts);
  k_scan<<<1, 1024, 0, stream>>>(counts, offsets);
  k_copy_i32<<<(NSEG + 255) / 256, 256, 0, stream>>>(offsets, counts, NSEG); // counts = cursors
  k_fill<<<(NEDGE + 255) / 256, 256, 0, stream>>>(ei, et, counts, ssrc);

  // ---- weights: zero pads once (transposes never touch pad rows/cols) ----
  long long wtot = 3LL * W1SLOT + 3LL * W2SLOT + (long long)N3PAD * K3P;
  k_zero_u16v<<<(unsigned)((wtot / 8 + 255) / 256), 256, 0, stream>>>(W1P, wtot / 8);
  dim3 tb(32, 8);
  dim3 g_t1((IN_DIM + 31) / 32, (DD1 + 31) / 32);
  dim3 g_t2((DD1 + 31) / 32, (DD2 + 31) / 32);

  // ---- input features ----
  k_build_xf<<<NN, 256, 0, stream>>>(x, gene, XF);

  // XCD-chunked 1D grids: 8 * ceil(MT/8) * ntiles
  const int Ma8 = 8 * ((MT + 7) / 8);          // 72
  const int gP1 = Ma8 * (2 * N1PAD / 128);     // 1584
  const int gR1 = Ma8 * (N1PAD / 128);         // 792
  const int gP2 = Ma8 * (2 * N2PAD / 128);     // 1152
  const int gR2 = Ma8 * (N2PAD / 128);         // 576
  const int gL3 = Ma8 * (N3PAD / 128);         // 432

  // ---- layer 1 ----
  k_transpose<<<g_t1, tb, 0, stream>>>(w_rel1,                            IN_DIM, DD1, W1P,          K1P);
  k_transpose<<<g_t1, tb, 0, stream>>>(w_rel1 + (long long)IN_DIM * DD1,  IN_DIM, DD1, W1P + W1SLOT, K1P);
  k_gemm<<<gP1, 256, 0, stream>>>(XF, K1P, W1P, K1P, K1P / 32,
      T, 2 * N1PAD, (const u16*)nullptr, 0, 2 * N1PAD, 2 * N1PAD, NN,
      (const float*)nullptr, 0, 0, MT, 2 * N1PAD / 128);
  k_agg2<<<NN, 256, 0, stream>>>(T, 2 * N1PAD, N1PAD, HACC, K2P, DD1, offsets, ssrc, 0, 1);
  k_transpose<<<g_t1, tb, 0, stream>>>(w_rel1 + 2LL * IN_DIM * DD1, IN_DIM, DD1, W1P,          K1P);
  k_transpose<<<g_t1, tb, 0, stream>>>(w_rel1 + 3LL * IN_DIM * DD1, IN_DIM, DD1, W1P + W1SLOT, K1P);
  k_gemm<<<gP1, 256, 0, stream>>>(XF, K1P, W1P, K1P, K1P / 32,
      T, 2 * N1PAD, (const u16*)nullptr, 0, 2 * N1PAD, 2 * N1PAD, NN,
      (const float*)nullptr, 0, 0, MT, 2 * N1PAD / 128);
  k_agg2<<<NN, 256, 0, stream>>>(T, 2 * N1PAD, N1PAD, HACC, K2P, DD1, offsets, ssrc, 2, 0);
  k_transpose<<<g_t1, tb, 0, stream>>>(root1, IN_DIM, DD1, W1R, K1P);
  k_gemm<<<gR1, 256, 0, stream>>>(XF, K1P, W1R, K1P, K1P / 32,
      H1, K2P, HACC, K2P, DD1, K2P, NN, b1, 1, 0, MT, N1PAD / 128);

  // ---- layer 2 ----
  k_transpose<<<g_t2, tb, 0, stream>>>(w_rel2,                          DD1, DD2, W2P,          K2P);
  k_transpose<<<g_t2, tb, 0, stream>>>(w_rel2 + (long long)DD1 * DD2,   DD1, DD2, W2P + W2SLOT, K2P);
  k_gemm<<<gP2, 256, 0, stream>>>(H1, K2P, W2P, K2P, K2P / 32,
      T, 2 * N2PAD, (const u16*)nullptr, 0, 2 * N2PAD, 2 * N2PAD, NN,
      (const float*)nullptr, 0, 0, MT, 2 * N2PAD / 128);
  k_agg2<<<NN, 256, 0, stream>>>(T, 2 * N2PAD, N2PAD, HACC, K3P, DD2, offsets, ssrc, 0, 1);
  k_transpose<<<g_t2, tb, 0, stream>>>(w_rel2 + 2LL * DD1 * DD2, DD1, DD2, W2P,          K2P);
  k_transpose<<<g_t2, tb, 0, stream>>>(w_rel2 + 3LL * DD1 * DD2, DD1, DD2, W2P + W2SLOT, K2P);
  k_gemm<<<gP2, 256, 0, stream>>>(H1, K2P, W2P, K2P, K2P / 32,
      T, 2 * N2PAD, (const u16*)nullptr, 0, 2 * N2PAD, 2 * N2PAD, NN,
      (const float*)nullptr, 0, 0, MT, 2 * N2PAD / 128);
  k_agg2<<<NN, 256, 0, stream>>>(T, 2 * N2PAD, N2PAD, HACC, K3P, DD2, offsets, ssrc, 2, 0);
  k_transpose<<<g_t2, tb, 0, stream>>>(root2, DD1, DD2, W2R, K2P);
  k_gemm<<<gR2, 256, 0, stream>>>(H1, K2P, W2R, K2P, K2P / 32,
      H2, K3P, HACC, K3P, DD2, K3P, NN, b2, 1, 0, MT, N2PAD / 128);

  // ---- lin1 -> emb (f32, straight into d_out) ----
  k_transpose<<<dim3((DD2 + 31) / 32, (DD3 + 31) / 32), tb, 0, stream>>>(lin1_w, DD2, DD3, W3T, K3P);
  k_gemm<<<gL3, 256, 0, stream>>>(H2, K3P, W3T, K3P, K3P / 32,
      emb, DD3, (const u16*)nullptr, 0, DD3, DD3, NN, lin1_b, 1, 1, MT, N3PAD / 128);

  // ---- lin2 + log_softmax ----
  k_lin2<<<(NN + 3) / 4, 256, 0, stream>>>(emb, lin2_w, lin2_b, out);
}

// Round 5
// 1198.215 us; speedup vs baseline: 1.2336x; 1.0206x over previous
//
#include <hip/hip_runtime.h>
#include <math.h>

// ---------------- problem constants ----------------
#define N_DRUGS 4000
#define NN      8264            // total nodes
#define IN_DIM  1613
#define NRELS   4
#define DD1     1340
#define DD2     920
#define DD3     740
#define NEDGE   100000
#define NSEG    (NN * NRELS)    // 33056

// padded dims
#define K1P     1632            // IN_DIM -> 51*32
#define K2P     1344            // DD1 -> 42*32
#define K3P     928             // DD2 -> 29*32
#define N1PAD   1408            // DD1 -> 11*128 (weight slot width)
#define N2PAD   1024            // DD2 -> 8*128
#define N3PAD   768             // DD3 -> 6*128
#define MT      65              // ceil(NN/128)

typedef unsigned short u16;
typedef __attribute__((ext_vector_type(8))) short short8;
typedef __attribute__((ext_vector_type(4))) float floatx4;

__device__ __forceinline__ u16 f2bf(float f) {
  union { float f; unsigned u; } v; v.f = f;
  unsigned u = v.u + 0x7fffu + ((v.u >> 16) & 1u);   // RNE
  return (u16)(u >> 16);
}
__device__ __forceinline__ float bf2f(u16 h) {
  union { unsigned u; float f; } v; v.u = ((unsigned)h) << 16;
  return v.f;
}

// ---------------- small utility kernels ----------------
__global__ void k_zero_i32(int* p, int n) {
  int i = blockIdx.x * 256 + threadIdx.x;
  if (i < n) p[i] = 0;
}

__global__ void k_zero_u16v(u16* p, long long nvec) {  // zeros 8 u16 per thread
  long long i = (long long)blockIdx.x * 256 + threadIdx.x;
  if (i < nvec) {
    short8 z = {0,0,0,0,0,0,0,0};
    *((short8*)p + i) = z;
  }
}

__global__ void k_copy_i32(const int* a, int* b, int n) {
  int i = blockIdx.x * 256 + threadIdx.x;
  if (i < n) b[i] = a[i];
}

// ---------------- CSR build (counting sort by segment = dst*4 + rel) ------
__global__ void k_hist(const int* __restrict__ ei, const int* __restrict__ et,
                       int* __restrict__ counts) {
  int e = blockIdx.x * 256 + threadIdx.x;
  if (e < NEDGE) {
    int dst = ei[NEDGE + e];
    atomicAdd(&counts[dst * 4 + et[e]], 1);
  }
}

__global__ void k_scan(const int* __restrict__ counts, int* __restrict__ offsets) {
  __shared__ int part[1024];
  int tid = threadIdx.x;
  const int chunk = (NSEG + 1023) / 1024;  // 33
  int lo = tid * chunk, hi = min(lo + chunk, NSEG);
  int s = 0;
  for (int i = lo; i < hi; i++) s += counts[i];
  part[tid] = s;
  __syncthreads();
  for (int off = 1; off < 1024; off <<= 1) {
    int v = (tid >= off) ? part[tid - off] : 0;
    __syncthreads();
    part[tid] += v;
    __syncthreads();
  }
  int base = (tid == 0) ? 0 : part[tid - 1];
  for (int i = lo; i < hi; i++) { offsets[i] = base; base += counts[i]; }
  if (tid == 0) offsets[NSEG] = part[1023];
}

__global__ void k_fill(const int* __restrict__ ei, const int* __restrict__ et,
                       int* __restrict__ cursors, int* __restrict__ ssrc) {
  int e = blockIdx.x * 256 + threadIdx.x;
  if (e < NEDGE) {
    int src = ei[e], dst = ei[NEDGE + e];
    int pos = atomicAdd(&cursors[dst * 4 + et[e]], 1);
    if (pos < NEDGE) ssrc[pos] = src;
  }
}

// ---------------- feature builder: xf = concat(x, gene_emb) in bf16 -------
__global__ void k_build_xf(const float* __restrict__ x, const float* __restrict__ gene,
                           u16* __restrict__ xf) {
  int n = blockIdx.x;
  const float* srow = (n < N_DRUGS) ? (x + (long long)n * IN_DIM)
                                    : (gene + (long long)(n - N_DRUGS) * IN_DIM);
  u16* dst = xf + (long long)n * K1P;
  for (int f = threadIdx.x; f < K1P; f += 256)
    dst[f] = (f < IN_DIM) ? f2bf(srow[f]) : (u16)0;
}

// f32 (K x N, row-major) -> bf16 out[n][k], tiled transpose; batched over z
__global__ void k_transpose(const float* __restrict__ in, int K, int N,
                            u16* __restrict__ out, int ldd,
                            long long strideIn, long long strideOut) {
  __shared__ float t[32][33];
  const float* inp = in + (long long)blockIdx.z * strideIn;
  u16* outp = out + (long long)blockIdx.z * strideOut;
  int k0 = blockIdx.x * 32, n0 = blockIdx.y * 32;
  int tx = threadIdx.x, ty = threadIdx.y;
  for (int i = ty; i < 32; i += 8) {
    int k = k0 + i, n = n0 + tx;
    t[i][tx] = (k < K && n < N) ? inp[(long long)k * N + n] : 0.f;
  }
  __syncthreads();
  for (int i = ty; i < 32; i += 8) {
    int n = n0 + i, k = k0 + tx;
    if (n < N && k < K) outp[(long long)n * ldd + k] = f2bf(t[tx][i]);
  }
}

// per-node mean over gathered T rows for TWO relations (slots 0 and slotOfs),
// accumulate into bf16 HACC
__global__ void k_agg2(const u16* __restrict__ T, int ldT, int slotOfs,
                       u16* __restrict__ HACC, int ldH, int F,
                       const int* __restrict__ offsets, const int* __restrict__ ssrc,
                       int rbase, int init) {
  int node = blockIdx.x;
  int s0 = node * 4 + rbase;
  int b0 = offsets[s0],     e0 = offsets[s0 + 1];
  int b1 = offsets[s0 + 1], e1 = offsets[s0 + 2];
  float inv0 = (e0 > b0) ? 1.0f / (float)(e0 - b0) : 0.0f;
  float inv1 = (e1 > b1) ? 1.0f / (float)(e1 - b1) : 0.0f;
  u16* o = HACC + (long long)node * ldH;
  for (int f = threadIdx.x; f < F; f += 256) {
    float a0 = 0.f, a1 = 0.f;
    for (int e = b0; e < e0; e++)
      a0 += bf2f(T[(long long)ssrc[e] * ldT + f]);
    for (int e = b1; e < e1; e++)
      a1 += bf2f(T[(long long)ssrc[e] * ldT + slotOfs + f]);
    float v = a0 * inv0 + a1 * inv1;
    if (!init) v += bf2f(o[f]);
    o[f] = f2bf(v);
  }
}

// ---------------- bf16 MFMA GEMM: C = act(A @ B^T + Cacc + bias) ----------
// Ping-pong double-buffered LDS, ONE barrier per k-step: iteration ks reads
// fragments + MFMAs from buffer (ks&1) while storing the register-prefetched
// tile k+1 into the other buffer, then a single __syncthreads. Register
// prefetch for k+2 is issued right after the ds_writes consume the regs.
// Chunk-swizzled unpadded [128][32] tiles -> 0 bank conflicts (verified r3/r4).
// XCD-chunked 1D grid: XCD r owns m-tiles m%8==r, n is the slow dimension.
#define TBUF (128 * 32)

__global__ __launch_bounds__(256)
void k_gemm(const u16* __restrict__ A, int lda,
            const u16* __restrict__ B, int ldb, int ksteps,
            void* __restrict__ Cout, int ldc,
            const u16* __restrict__ Cacc, int ldacc,
            int nreal, int nlimit, int mlimit,
            const float* __restrict__ bias, int relu, int f32out,
            int mtiles, int ntiles)
{
  int f = blockIdx.x;
  int xr = f & 7, q = f >> 3;
  int Ma = (mtiles + 7) >> 3;
  int ncol = q / Ma;
  int mi = ((q - ncol * Ma) << 3) + xr;
  if (mi >= mtiles) return;

  __shared__ __align__(16) u16 At[2 * TBUF];
  __shared__ __align__(16) u16 Bt[2 * TBUF];
  int tid = threadIdx.x;
  int wave = tid >> 6, lane = tid & 63;
  int wm = (wave >> 1) << 6, wn = (wave & 1) << 6;
  int qd = lane >> 4, l16 = lane & 15;

  const u16* Ag = A + (long long)mi * 128 * lda;
  const u16* Bg = B + (long long)ncol * 128 * ldb;

  int row = tid >> 2, cc = tid & 3;           // 64 rows x 4 chunks per 256 threads
  int swc = cc ^ ((row >> 1) & 3);            // same swizzle for row and row+64
  const u16* gA0 = Ag + (long long)row * lda + cc * 8;
  const u16* gA1 = Ag + (long long)(row + 64) * lda + cc * 8;
  const u16* gB0 = Bg + (long long)row * ldb + cc * 8;
  const u16* gB1 = Bg + (long long)(row + 64) * ldb + cc * 8;
  int wA0 = row * 32 + swc * 8;               // LDS write offsets (within a buffer)
  int wA1 = (row + 64) * 32 + swc * 8;
  int rofs = ((qd ^ ((l16 >> 1) & 3)) << 3);  // fragment read chunk offset

  // k=0 into registers, store to buffer 0
  short8 pa0 = *(const short8*)gA0;
  short8 pa1 = *(const short8*)gA1;
  short8 pb0 = *(const short8*)gB0;
  short8 pb1 = *(const short8*)gB1;
  *(short8*)(At + wA0) = pa0; *(short8*)(At + wA1) = pa1;
  *(short8*)(Bt + wA0) = pb0; *(short8*)(Bt + wA1) = pb1;
  if (ksteps > 1) {                            // prefetch k=1
    pa0 = *(const short8*)(gA0 + 32); pa1 = *(const short8*)(gA1 + 32);
    pb0 = *(const short8*)(gB0 + 32); pb1 = *(const short8*)(gB1 + 32);
  }
  __syncthreads();

  floatx4 acc[4][4] = {};

  for (int ks = 0; ks < ksteps; ks++) {
    const u16* Ac = At + (ks & 1) * TBUF;
    const u16* Bc = Bt + (ks & 1) * TBUF;
    short8 af[4], bfr[4];
#pragma unroll
    for (int i = 0; i < 4; i++)
      af[i] = *(const short8*)(Ac + (wm + i * 16 + l16) * 32 + rofs);
#pragma unroll
    for (int j = 0; j < 4; j++)
      bfr[j] = *(const short8*)(Bc + (wn + j * 16 + l16) * 32 + rofs);
#pragma unroll
    for (int i = 0; i < 4; i++)
#pragma unroll
      for (int j = 0; j < 4; j++)
        acc[i][j] = __builtin_amdgcn_mfma_f32_16x16x32_bf16(af[i], bfr[j], acc[i][j], 0, 0, 0);
    if (ks + 1 < ksteps) {
      u16* An = At + ((ks + 1) & 1) * TBUF;
      u16* Bn = Bt + ((ks + 1) & 1) * TBUF;
      *(short8*)(An + wA0) = pa0; *(short8*)(An + wA1) = pa1;
      *(short8*)(Bn + wA0) = pb0; *(short8*)(Bn + wA1) = pb1;
      if (ks + 2 < ksteps) {                  // prefetch k+2
        int kb = (ks + 2) * 32;
        pa0 = *(const short8*)(gA0 + kb); pa1 = *(const short8*)(gA1 + kb);
        pb0 = *(const short8*)(gB0 + kb); pb1 = *(const short8*)(gB1 + kb);
      }
    }
    __syncthreads();
  }

  // epilogue
#pragma unroll
  for (int i = 0; i < 4; i++) {
#pragma unroll
    for (int j = 0; j < 4; j++) {
      int col = ncol * 128 + wn + j * 16 + l16;
      if (col >= nlimit) continue;
      float bv = (bias && col < nreal) ? bias[col] : 0.f;
#pragma unroll
      for (int rg = 0; rg < 4; rg++) {
        int rowc = mi * 128 + wm + i * 16 + qd * 4 + rg;
        if (rowc >= mlimit) continue;
        float v = 0.f;
        if (col < nreal) {
          v = acc[i][j][rg] + bv;
          if (Cacc) v += bf2f(Cacc[(long long)rowc * ldacc + col]);
          if (relu) v = fmaxf(v, 0.f);
        }
        if (f32out) ((float*)Cout)[(long long)rowc * ldc + col] = v;
        else        ((u16*)Cout)[(long long)rowc * ldc + col] = f2bf(v);
      }
    }
  }
}

// ---------------- final tiny layer: logits + log_softmax ----------------
__global__ void k_lin2(const float* __restrict__ emb, const float* __restrict__ w,
                       const float* __restrict__ b, float* __restrict__ out) {
  int node = blockIdx.x * 4 + (threadIdx.x >> 6);
  int lane = threadIdx.x & 63;
  if (node >= NN) return;
  const float* e = emb + (long long)node * DD3;
  float a0 = 0.f, a1 = 0.f;
  for (int f = lane; f < DD3; f += 64) {
    float v = e[f];
    a0 += v * w[2 * f];
    a1 += v * w[2 * f + 1];
  }
  for (int off = 32; off > 0; off >>= 1) {
    a0 += __shfl_down(a0, off);
    a1 += __shfl_down(a1, off);
  }
  if (lane == 0) {
    a0 += b[0]; a1 += b[1];
    float m = fmaxf(a0, a1);
    float ls = m + logf(expf(a0 - m) + expf(a1 - m));
    out[(long long)node * 2]     = a0 - ls;
    out[(long long)node * 2 + 1] = a1 - ls;
  }
}

// ---------------- launch ----------------
extern "C" void kernel_launch(void* const* d_in, const int* in_sizes, int n_in,
                              void* d_out, int out_size, void* d_ws, size_t ws_size,
                              hipStream_t stream)
{
  const float* x      = (const float*)d_in[0];
  const float* gene   = (const float*)d_in[1];
  const float* w_rel1 = (const float*)d_in[2];
  const float* root1  = (const float*)d_in[3];
  const float* b1     = (const float*)d_in[4];
  const float* w_rel2 = (const float*)d_in[5];
  const float* root2  = (const float*)d_in[6];
  const float* b2     = (const float*)d_in[7];
  const float* lin1_w = (const float*)d_in[8];
  const float* lin1_b = (const float*)d_in[9];
  const float* lin2_w = (const float*)d_in[10];
  const float* lin2_b = (const float*)d_in[11];
  const int*   ei     = (const int*)d_in[12];
  const int*   et     = (const int*)d_in[13];
  float* out = (float*)d_out;

  // workspace layout (~142 MB total; known-good budget 155.6 MB)
  char* ws = (char*)d_ws;
  size_t off = 0;
  auto alloc = [&](size_t bytes) -> void* {
    void* p = ws + off;
    off += (bytes + 255) & ~(size_t)255;
    return p;
  };
  const size_t W1SLOT = (size_t)N1PAD * K1P;
  const size_t W2SLOT = (size_t)N2PAD * K2P;
  u16* XF   = (u16*)alloc((size_t)NN * K1P * 2);     // reused as H2 (NN x K3P) later
  u16* T    = (u16*)alloc((size_t)NN * 2 * N1PAD * 2); // 2-slot transform output
  u16* HACC = (u16*)alloc((size_t)NN * K2P * 2);     // bf16 aggregation accumulator
  u16* H1   = (u16*)alloc((size_t)NN * K2P * 2);
  u16* W1P  = (u16*)alloc(2 * W1SLOT * 2);           // pair slot (reused r0r1 -> r2r3)
  u16* W1R  = (u16*)alloc(W1SLOT * 2);               // root slot
  u16* W2P  = (u16*)alloc(2 * W2SLOT * 2);
  u16* W2R  = (u16*)alloc(W2SLOT * 2);
  u16* W3T  = (u16*)alloc((size_t)N3PAD * K3P * 2);
  int* counts  = (int*)alloc((NSEG + 1) * 4);        // reused as cursors
  int* offsets = (int*)alloc((NSEG + 1) * 4);
  int* ssrc    = (int*)alloc((size_t)NEDGE * 4);
  u16* H2 = XF;                                      // alias: XF dead after L1 root GEMM
  float* emb = out + 2 * NN;   // d_out = [log_softmax 8264x2][emb 8264x740]

  if (off > ws_size) return;   // diagnostic: stub-like absmax instead of GPU fault

  // ---- CSR build ----
  k_zero_i32<<<(NSEG + 1 + 255) / 256, 256, 0, stream>>>(counts, NSEG + 1);
  k_hist<<<(NEDGE + 255) / 256, 256, 0, stream>>>(ei, et, counts);
  k_scan<<<1, 1024, 0, stream>>>(counts, offsets);
  k_copy_i32<<<(NSEG + 255) / 256, 256, 0, stream>>>(offsets, counts, NSEG); // counts = cursors
  k_fill<<<(NEDGE + 255) / 256, 256, 0, stream>>>(ei, et, counts, ssrc);

  // ---- weights: zero pads once (transposes never touch pad rows/cols) ----
  long long wtot = 3LL * W1SLOT + 3LL * W2SLOT + (long long)N3PAD * K3P;
  k_zero_u16v<<<(unsigned)((wtot / 8 + 255) / 256), 256, 0, stream>>>(W1P, wtot / 8);
  dim3 tb(32, 8);
  dim3 g_t1((IN_DIM + 31) / 32, (DD1 + 31) / 32, 2);
  dim3 g_t1s((IN_DIM + 31) / 32, (DD1 + 31) / 32, 1);
  dim3 g_t2((DD1 + 31) / 32, (DD2 + 31) / 32, 2);
  dim3 g_t2s((DD1 + 31) / 32, (DD2 + 31) / 32, 1);

  // ---- input features ----
  k_build_xf<<<NN, 256, 0, stream>>>(x, gene, XF);

  // XCD-chunked 1D grids: 8 * ceil(MT/8) * ntiles
  const int Ma8 = 8 * ((MT + 7) / 8);          // 72
  const int gP1 = Ma8 * (2 * N1PAD / 128);     // 1584
  const int gR1 = Ma8 * (N1PAD / 128);         // 792
  const int gP2 = Ma8 * (2 * N2PAD / 128);     // 1152
  const int gR2 = Ma8 * (N2PAD / 128);         // 576
  const int gL3 = Ma8 * (N3PAD / 128);         // 432

  // ---- layer 1 ----
  k_transpose<<<g_t1, tb, 0, stream>>>(w_rel1, IN_DIM, DD1, W1P, K1P,
                                       (long long)IN_DIM * DD1, (long long)W1SLOT);
  k_gemm<<<gP1, 256, 0, stream>>>(XF, K1P, W1P, K1P, K1P / 32,
      T, 2 * N1PAD, (const u16*)nullptr, 0, 2 * N1PAD, 2 * N1PAD, NN,
      (const float*)nullptr, 0, 0, MT, 2 * N1PAD / 128);
  k_agg2<<<NN, 256, 0, stream>>>(T, 2 * N1PAD, N1PAD, HACC, K2P, DD1, offsets, ssrc, 0, 1);
  k_transpose<<<g_t1, tb, 0, stream>>>(w_rel1 + 2LL * IN_DIM * DD1, IN_DIM, DD1, W1P, K1P,
                                       (long long)IN_DIM * DD1, (long long)W1SLOT);
  k_gemm<<<gP1, 256, 0, stream>>>(XF, K1P, W1P, K1P, K1P / 32,
      T, 2 * N1PAD, (const u16*)nullptr, 0, 2 * N1PAD, 2 * N1PAD, NN,
      (const float*)nullptr, 0, 0, MT, 2 * N1PAD / 128);
  k_agg2<<<NN, 256, 0, stream>>>(T, 2 * N1PAD, N1PAD, HACC, K2P, DD1, offsets, ssrc, 2, 0);
  k_transpose<<<g_t1s, tb, 0, stream>>>(root1, IN_DIM, DD1, W1R, K1P, 0, 0);
  k_gemm<<<gR1, 256, 0, stream>>>(XF, K1P, W1R, K1P, K1P / 32,
      H1, K2P, HACC, K2P, DD1, K2P, NN, b1, 1, 0, MT, N1PAD / 128);

  // ---- layer 2 ----
  k_transpose<<<g_t2, tb, 0, stream>>>(w_rel2, DD1, DD2, W2P, K2P,
                                       (long long)DD1 * DD2, (long long)W2SLOT);
  k_gemm<<<gP2, 256, 0, stream>>>(H1, K2P, W2P, K2P, K2P / 32,
      T, 2 * N2PAD, (const u16*)nullptr, 0, 2 * N2PAD, 2 * N2PAD, NN,
      (const float*)nullptr, 0, 0, MT, 2 * N2PAD / 128);
  k_agg2<<<NN, 256, 0, stream>>>(T, 2 * N2PAD, N2PAD, HACC, K3P, DD2, offsets, ssrc, 0, 1);
  k_transpose<<<g_t2, tb, 0, stream>>>(w_rel2 + 2LL * DD1 * DD2, DD1, DD2, W2P, K2P,
                                       (long long)DD1 * DD2, (long long)W2SLOT);
  k_gemm<<<gP2, 256, 0, stream>>>(H1, K2P, W2P, K2P, K2P / 32,
      T, 2 * N2PAD, (const u16*)nullptr, 0, 2 * N2PAD, 2 * N2PAD, NN,
      (const float*)nullptr, 0, 0, MT, 2 * N2PAD / 128);
  k_agg2<<<NN, 256, 0, stream>>>(T, 2 * N2PAD, N2PAD, HACC, K3P, DD2, offsets, ssrc, 2, 0);
  k_transpose<<<g_t2s, tb, 0, stream>>>(root2, DD1, DD2, W2R, K2P, 0, 0);
  k_gemm<<<gR2, 256, 0, stream>>>(H1, K2P, W2R, K2P, K2P / 32,
      H2, K3P, HACC, K3P, DD2, K3P, NN, b2, 1, 0, MT, N2PAD / 128);

  // ---- lin1 -> emb (f32, straight into d_out) ----
  k_transpose<<<dim3((DD2 + 31) / 32, (DD3 + 31) / 32, 1), tb, 0, stream>>>(
      lin1_w, DD2, DD3, W3T, K3P, 0, 0);
  k_gemm<<<gL3, 256, 0, stream>>>(H2, K3P, W3T, K3P, K3P / 32,
      emb, DD3, (const u16*)nullptr, 0, DD3, DD3, NN, lin1_b, 1, 1, MT, N3PAD / 128);

  // ---- lin2 + log_softmax ----
  k_lin2<<<(NN + 3) / 4, 256, 0, stream>>>(emb, lin2_w, lin2_b, out);
}